// Round 3
// baseline (771.259 us; speedup 1.0000x reference)
//
#include <hip/hip_runtime.h>

#define E_DIM  256
#define N_E    16384
#define N_ROWS 8192
#define HW     1024
#define NPART  128          // n-tiles of 128 cols
#define BMT    256          // block m-tile
#define BNT    128          // block n-tile

typedef _Float16 f16x8 __attribute__((ext_vector_type(8)));
typedef _Float16 f16x4 __attribute__((ext_vector_type(4)));
typedef float    f32x4 __attribute__((ext_vector_type(4)));

#define ESCALE   1048576.0f          // 2^20 (exact)
#define UNSCALE  1.9073486328125e-6f // 2^-19: acc*2^-19 == 2*dot

// ---------- prep: E row -> fp16 limbs (scaled) + ||e||^2 in numpy pairwise order ----------
__global__ __launch_bounds__(256) void k_e_prep(const float* __restrict__ E,
                                                _Float16* __restrict__ eh,
                                                _Float16* __restrict__ el,
                                                float* __restrict__ eNorm) {
#pragma clang fp contract(off)
  int k = blockIdx.x * 256 + threadIdx.x;
  const float* a = E + (size_t)k * E_DIM;
  float halves[2];
  for (int h = 0; h < 2; ++h) {
    const float* p = a + h * 128;
    float r[8] = {0.f, 0.f, 0.f, 0.f, 0.f, 0.f, 0.f, 0.f};
    for (int i = 0; i < 128; i += 8) {
      float4 v0 = *(const float4*)&p[i];
      float4 v1 = *(const float4*)&p[i + 4];
      float v[8] = {v0.x, v0.y, v0.z, v0.w, v1.x, v1.y, v1.z, v1.w};
      f16x8 hh, ll;
#pragma unroll
      for (int j = 0; j < 8; ++j) {
        r[j] = r[j] + v[j] * v[j];
        float s = v[j] * ESCALE;
        _Float16 hi = (_Float16)s;
        hh[j] = hi;
        ll[j] = (_Float16)(s - (float)hi);
      }
      *(f16x8*)&eh[(size_t)k * E_DIM + h * 128 + i] = hh;
      *(f16x8*)&el[(size_t)k * E_DIM + h * 128 + i] = ll;
    }
    halves[h] = ((r[0] + r[1]) + (r[2] + r[3])) + ((r[4] + r[5]) + (r[6] + r[7]));
  }
  eNorm[k] = halves[0] + halves[1];
}

// ---------- prep: z (b,c,hw) -> [n][c] fp16 limbs + ||z||^2 in numpy pairwise order ----------
__global__ __launch_bounds__(256) void k_z_prep(const float* __restrict__ z,
                                                _Float16* __restrict__ zh,
                                                _Float16* __restrict__ zl,
                                                float* __restrict__ zNorm) {
#pragma clang fp contract(off)
  int n = blockIdx.x * 256 + threadIdx.x;
  int b = n >> 10, hw = n & 1023;
  const float* p = z + (size_t)b * E_DIM * HW + hw;
  float halves[2];
  for (int h = 0; h < 2; ++h) {
    const float* a = p + (size_t)h * 128 * HW;
    float r[8] = {0.f, 0.f, 0.f, 0.f, 0.f, 0.f, 0.f, 0.f};
    for (int i = 0; i < 128; i += 8) {
      f16x8 hh, ll;
#pragma unroll
      for (int j = 0; j < 8; ++j) {
        float v = a[(size_t)(i + j) * HW];
        r[j] = r[j] + v * v;
        _Float16 hi = (_Float16)v;
        hh[j] = hi;
        ll[j] = (_Float16)(v - (float)hi);
      }
      *(f16x8*)&zh[(size_t)n * E_DIM + h * 128 + i] = hh;
      *(f16x8*)&zl[(size_t)n * E_DIM + h * 128 + i] = ll;
    }
    halves[h] = ((r[0] + r[1]) + (r[2] + r[3])) + ((r[4] + r[5]) + (r[6] + r[7]));
  }
  zNorm[n] = halves[0] + halves[1];
}

// ---------- main: 3-pass fp16-limb MFMA GEMM, block 256x128, wave 128x64 ----------
__global__ __launch_bounds__(256, 2) void k_scores_mfma(
    const _Float16* __restrict__ zh, const _Float16* __restrict__ zl,
    const _Float16* __restrict__ eh, const _Float16* __restrict__ el,
    const float* __restrict__ eNorm, const float* __restrict__ zNorm,
    float* __restrict__ pVal, int* __restrict__ pIdx) {
#pragma clang fp contract(off)
  __shared__ alignas(16) _Float16 As[2][BMT][40];  // 40960 B (pitch 20 dwords)
  __shared__ alignas(16) _Float16 Bs[2][BNT][40];  // 20480 B

  const int mt = blockIdx.x, nt = blockIdx.y;
  const int m0 = mt * BMT, n0 = nt * BNT;

  const int t = threadIdx.x;
  const int lane = t & 63, w = t >> 6;
  const int tx = lane & 15, quad = lane >> 4;
  const int wm = (w >> 1) * 128, wn = (w & 1) * 64;

  // staging assignment: thread t stages A row t (both limbs) + B unit (limb t>>7, row t&127)
  const int blimb = t >> 7, brow = t & 127;
  const _Float16* bsrc = blimb ? el : eh;

  f32x4 acc[8][4];
#pragma unroll
  for (int i = 0; i < 8; ++i)
#pragma unroll
    for (int j = 0; j < 4; ++j) acc[i][j] = (f32x4){0.f, 0.f, 0.f, 0.f};

  for (int kc = 0; kc < 8; ++kc) {
    const int k0 = kc * 32;
    // global loads (issue before sync; vmcnt overlaps with previous iter's MFMA)
    const size_t ab = (size_t)(m0 + t) * E_DIM + k0;
    const size_t bb = (size_t)(n0 + brow) * E_DIM + k0;
    float4 rah[4], ral[4], rb[4];
#pragma unroll
    for (int s = 0; s < 4; ++s) {
      rah[s] = *(const float4*)&zh[ab + s * 8];
      ral[s] = *(const float4*)&zl[ab + s * 8];
      rb[s]  = *(const float4*)&bsrc[bb + s * 8];
    }
    __syncthreads();   // previous iteration's frag reads done
#pragma unroll
    for (int s = 0; s < 4; ++s) {
      *(float4*)&As[0][t][s * 8]     = rah[s];
      *(float4*)&As[1][t][s * 8]     = ral[s];
      *(float4*)&Bs[blimb][brow][s * 8] = rb[s];
    }
    __syncthreads();

    f16x8 bh[4], bl[4];
#pragma unroll
    for (int j = 0; j < 4; ++j) {
      bh[j] = *(const f16x8*)&Bs[0][wn + j * 16 + tx][quad * 8];
      bl[j] = *(const f16x8*)&Bs[1][wn + j * 16 + tx][quad * 8];
    }
#pragma unroll
    for (int i = 0; i < 8; ++i) {
      f16x8 ah = *(const f16x8*)&As[0][wm + i * 16 + tx][quad * 8];
      f16x8 al = *(const f16x8*)&As[1][wm + i * 16 + tx][quad * 8];
#pragma unroll
      for (int j = 0; j < 4; ++j) {
        acc[i][j] = __builtin_amdgcn_mfma_f32_16x16x32_f16(ah, bh[j], acc[i][j], 0, 0, 0);
        acc[i][j] = __builtin_amdgcn_mfma_f32_16x16x32_f16(ah, bl[j], acc[i][j], 0, 0, 0);
        acc[i][j] = __builtin_amdgcn_mfma_f32_16x16x32_f16(al, bh[j], acc[i][j], 0, 0, 0);
      }
    }
  }

  // ---- epilogue: score + argmin (first-index tie-break) ----
  __syncthreads();
  float* sV  = (float*)&As[0][0][0];      // [2][256]
  int*   sI  = (int*)(sV + 512);          // [2][256]
  float* zNl = (float*)&Bs[0][0][0];      // [256]
  float* eNl = zNl + 256;                 // [128]
  zNl[t] = zNorm[m0 + t];
  if (t < 128) eNl[t] = eNorm[n0 + t];
  __syncthreads();

#pragma unroll
  for (int i = 0; i < 8; ++i) {
#pragma unroll
    for (int r = 0; r < 4; ++r) {
      const int rloc = wm + i * 16 + quad * 4 + r;
      const float zn = zNl[rloc];
      float bv = 3.4e38f;
      int bc = 0x7fffffff;
#pragma unroll
      for (int j = 0; j < 4; ++j) {
        const int col = wn + j * 16 + tx;
        float s = (zn + eNl[col]) - acc[i][j][r] * UNSCALE;
        if (s < bv) { bv = s; bc = n0 + col; }   // j ascending: strict < keeps lowest col
      }
#pragma unroll
      for (int off = 1; off < 16; off <<= 1) {
        float ov = __shfl_xor(bv, off, 64);
        int oc = __shfl_xor(bc, off, 64);
        if (ov < bv || (ov == bv && oc < bc)) { bv = ov; bc = oc; }
      }
      if (tx == 0) { sV[(w & 1) * 256 + rloc] = bv; sI[(w & 1) * 256 + rloc] = bc; }
    }
  }
  __syncthreads();
  {
    float v0 = sV[t], v1 = sV[256 + t];
    int i0 = sI[t], i1 = sI[256 + t];
    int take1 = (v1 < v0);                 // tie -> half 0 (lower cols)
    pVal[(size_t)nt * N_ROWS + m0 + t] = take1 ? v1 : v0;
    pIdx[(size_t)nt * N_ROWS + m0 + t] = take1 ? i1 : i0;
  }
}

// ---------- finalize argmin across NPART partials (coalesced [nt][row] layout) ----------
__global__ __launch_bounds__(256) void k_finalize(const float* __restrict__ pVal,
                                                  const int* __restrict__ pIdx,
                                                  int* __restrict__ fIdx,
                                                  float* __restrict__ out_idx,
                                                  float* __restrict__ out_loss) {
  int n = blockIdx.x * 256 + threadIdx.x;
  float mv = 3.4e38f;
  int mi = 0x7fffffff;
  for (int s2 = 0; s2 < NPART; ++s2) {
    float v = pVal[(size_t)s2 * N_ROWS + n];
    int id = pIdx[(size_t)s2 * N_ROWS + n];
    if (v < mv || (v == mv && id < mi)) { mv = v; mi = id; }
  }
  fIdx[n] = mi;
  out_idx[n] = (float)mi;
  if (n == 0) out_loss[0] = 0.f;
}

// ---------- gather z_q to (b,c,h,w) + fused loss = 1.25*mean((zq-z)^2) ----------
__global__ __launch_bounds__(256) void k_gather_loss(
    const float* __restrict__ z, const float* __restrict__ E,
    const int* __restrict__ fIdx, float* __restrict__ out,
    float* __restrict__ out_loss) {
  int n = blockIdx.x * 256 + threadIdx.x;
  int b = n >> 10, hw = n & 1023;
  int idx = fIdx[n];
  const float* erow = E + (size_t)idx * E_DIM;
  const float* zrow = z + (size_t)b * E_DIM * HW + hw;
  float* orow = out + (size_t)b * E_DIM * HW + hw;
  float s = 0.f;
#pragma unroll 4
  for (int c = 0; c < E_DIM; ++c) {
    float e = erow[c];
    float zv = zrow[(size_t)c * HW];
    orow[(size_t)c * HW] = e;
    float d = e - zv;
    s = fmaf(d, d, s);
  }
  for (int off = 32; off > 0; off >>= 1) s += __shfl_down(s, off, 64);
  __shared__ float wsum[4];
  if ((threadIdx.x & 63) == 0) wsum[threadIdx.x >> 6] = s;
  __syncthreads();
  if (threadIdx.x == 0) {
    float tot = (wsum[0] + wsum[1]) + (wsum[2] + wsum[3]);
    atomicAdd(out_loss, tot * (1.25f / 2097152.f));
  }
}

extern "C" void kernel_launch(void* const* d_in, const int* in_sizes, int n_in,
                              void* d_out, int out_size, void* d_ws, size_t ws_size,
                              hipStream_t stream) {
  const float* z = (const float*)d_in[0];
  const float* E = (const float*)d_in[1];
  float* out = (float*)d_out;
  float* out_loss = out + 2097152;  // after z_q (8*256*32*32)
  float* out_idx = out + 2097153;

  // workspace: zh|zl f16[8192][256], eh|el f16[16384][256], eNorm, zNorm, pVal, pIdx, fIdx
  _Float16* zh = (_Float16*)d_ws;
  _Float16* zl = zh + (size_t)N_ROWS * E_DIM;
  _Float16* eh = zl + (size_t)N_ROWS * E_DIM;
  _Float16* el = eh + (size_t)N_E * E_DIM;
  float* eNorm = (float*)(el + (size_t)N_E * E_DIM);
  float* zNorm = eNorm + N_E;
  float* pVal = zNorm + N_ROWS;
  int* pIdx = (int*)(pVal + (size_t)NPART * N_ROWS);
  int* fIdx = pIdx + (size_t)NPART * N_ROWS;

  k_e_prep<<<N_E / 256, 256, 0, stream>>>(E, eh, el, eNorm);
  k_z_prep<<<N_ROWS / 256, 256, 0, stream>>>(z, zh, zl, zNorm);
  k_scores_mfma<<<dim3(N_ROWS / BMT, N_E / BNT), 256, 0, stream>>>(
      zh, zl, eh, el, eNorm, zNorm, pVal, pIdx);
  k_finalize<<<N_ROWS / 256, 256, 0, stream>>>(pVal, pIdx, fIdx, out_idx, out_loss);
  k_gather_loss<<<N_ROWS / 256, 256, 0, stream>>>(z, E, fIdx, out, out_loss);
}

// Round 4
// 414.602 us; speedup vs baseline: 1.8602x; 1.8602x over previous
//
#include <hip/hip_runtime.h>

#define E_DIM  256
#define N_E    16384
#define N_ROWS 8192
#define HW     1024
#define NPART  128          // n-tiles of 128 cols

typedef _Float16 f16x8 __attribute__((ext_vector_type(8)));
typedef float    f32x4 __attribute__((ext_vector_type(4)));

#define ESCALE   1048576.0f          // 2^20 (exact)
#define UNSCALE  1.9073486328125e-6f // 2^-19: acc*2^-19 == 2*dot

// async 16B global->LDS copy: LDS dst = wave-uniform base + lane*16
__device__ __forceinline__ void gld_lds16(_Float16* lds, const _Float16* g) {
  __builtin_amdgcn_global_load_lds(
      (__attribute__((address_space(1))) void*)(g),
      (__attribute__((address_space(3))) void*)(lds), 16, 0, 0);
}

// ---------- prep: E -> kc-tiled swizzled fp16 limbs + ||e||^2 (numpy pairwise) ----------
// layout: Bh/Bl[kc][k][32 f16], 16B block q stored at physical block q^((k>>1)&3)
__global__ __launch_bounds__(256) void k_e_prep(const float* __restrict__ E,
                                                _Float16* __restrict__ Bh,
                                                _Float16* __restrict__ Bl,
                                                float* __restrict__ eNorm,
                                                float* __restrict__ out_loss) {
#pragma clang fp contract(off)
  int k = blockIdx.x * 256 + threadIdx.x;
  if (k == 0) out_loss[0] = 0.f;   // stream-ordered before k_post's atomics
  const float* a = E + (size_t)k * E_DIM;
  const int perm = (k >> 1) & 3;
  float halves[2];
  for (int h = 0; h < 2; ++h) {
    const float* p = a + h * 128;
    float r[8] = {0.f, 0.f, 0.f, 0.f, 0.f, 0.f, 0.f, 0.f};
    for (int i = 0; i < 128; i += 8) {
      float4 v0 = *(const float4*)&p[i];
      float4 v1 = *(const float4*)&p[i + 4];
      float v[8] = {v0.x, v0.y, v0.z, v0.w, v1.x, v1.y, v1.z, v1.w};
      f16x8 hh, ll;
#pragma unroll
      for (int j = 0; j < 8; ++j) {
        r[j] = r[j] + v[j] * v[j];
        float s = v[j] * ESCALE;
        _Float16 hi = (_Float16)s;
        hh[j] = hi;
        ll[j] = (_Float16)(s - (float)hi);
      }
      int c = h * 128 + i;                 // k-dim position (multiple of 8)
      int kc = c >> 5, q = (c >> 3) & 3;
      size_t dst = (size_t)kc * (N_E * 32) + (size_t)k * 32 + (size_t)(q ^ perm) * 8;
      *(f16x8*)&Bh[dst] = hh;
      *(f16x8*)&Bl[dst] = ll;
    }
    halves[h] = ((r[0] + r[1]) + (r[2] + r[3])) + ((r[4] + r[5]) + (r[6] + r[7]));
  }
  eNorm[k] = halves[0] + halves[1];
}

// ---------- prep: z (b,c,hw) -> kc-tiled swizzled limbs + ||z||^2 (numpy pairwise) ----------
__global__ __launch_bounds__(256) void k_z_prep(const float* __restrict__ z,
                                                _Float16* __restrict__ Ah,
                                                _Float16* __restrict__ Al,
                                                float* __restrict__ zNorm) {
#pragma clang fp contract(off)
  int n = blockIdx.x * 256 + threadIdx.x;
  int b = n >> 10, hw = n & 1023;
  const float* p = z + (size_t)b * E_DIM * HW + hw;
  const int perm = (n >> 1) & 3;
  float halves[2];
  for (int h = 0; h < 2; ++h) {
    const float* a = p + (size_t)h * 128 * HW;
    float r[8] = {0.f, 0.f, 0.f, 0.f, 0.f, 0.f, 0.f, 0.f};
    for (int i = 0; i < 128; i += 8) {
      f16x8 hh, ll;
#pragma unroll
      for (int j = 0; j < 8; ++j) {
        float v = a[(size_t)(i + j) * HW];
        r[j] = r[j] + v * v;
        _Float16 hi = (_Float16)v;
        hh[j] = hi;
        ll[j] = (_Float16)(v - (float)hi);
      }
      int c = h * 128 + i;
      int kc = c >> 5, q = (c >> 3) & 3;
      size_t dst = (size_t)kc * (N_ROWS * 32) + (size_t)n * 32 + (size_t)(q ^ perm) * 8;
      *(f16x8*)&Ah[dst] = hh;
      *(f16x8*)&Al[dst] = ll;
    }
    halves[h] = ((r[0] + r[1]) + (r[2] + r[3])) + ((r[4] + r[5]) + (r[6] + r[7]));
  }
  zNorm[n] = halves[0] + halves[1];
}

// ---------- main: 3-pass fp16-limb MFMA GEMM, block 128x128, wave 64x64 ----------
// A/B staged via global_load_lds (async DMA), swizzled layout -> conflict-free b128 frag reads
__global__ __launch_bounds__(256, 3) void k_scores_mfma(
    const _Float16* __restrict__ Ah, const _Float16* __restrict__ Al,
    const _Float16* __restrict__ Bh, const _Float16* __restrict__ Bl,
    const float* __restrict__ eNorm, const float* __restrict__ zNorm,
    float* __restrict__ pVal, int* __restrict__ pIdx) {
#pragma clang fp contract(off)
  __shared__ alignas(16) _Float16 As[2][128][32];  // 16 KB: limb, row, swizzled 32 f16
  __shared__ alignas(16) _Float16 Bs[2][128][32];  // 16 KB

  const int mt = blockIdx.x, nt = blockIdx.y;
  const int m0 = mt * 128, n0 = nt * 128;

  const int t = threadIdx.x;
  const int lane = t & 63, w = t >> 6;
  const int tx = lane & 15, quad = lane >> 4;
  const int wm = (w >> 1) * 64, wn = (w & 1) * 64;
  const int swz = (quad ^ ((tx >> 1) & 3)) * 8;    // physical f16 offset of logical block `quad`

  // per-wave staging segment (8 KB contiguous per kc-slab)
  const _Float16* gseg;
  size_t plane;
  _Float16* lseg;
  if (w == 0)      { gseg = Ah + (size_t)m0 * 32; plane = (size_t)N_ROWS * 32; lseg = &As[0][0][0]; }
  else if (w == 1) { gseg = Al + (size_t)m0 * 32; plane = (size_t)N_ROWS * 32; lseg = &As[1][0][0]; }
  else if (w == 2) { gseg = Bh + (size_t)n0 * 32; plane = (size_t)N_E * 32;    lseg = &Bs[0][0][0]; }
  else             { gseg = Bl + (size_t)n0 * 32; plane = (size_t)N_E * 32;    lseg = &Bs[1][0][0]; }

  f32x4 acc[4][4];
#pragma unroll
  for (int i = 0; i < 4; ++i)
#pragma unroll
    for (int j = 0; j < 4; ++j) acc[i][j] = (f32x4){0.f, 0.f, 0.f, 0.f};

  for (int kc = 0; kc < 8; ++kc) {
    __syncthreads();                       // previous iteration's frag reads done
    const _Float16* g = gseg + (size_t)kc * plane + lane * 8;
#pragma unroll
    for (int c = 0; c < 8; ++c)
      gld_lds16(lseg + c * 512, g + c * 512);   // 8 x 1KB async copies per wave
    __syncthreads();                       // vmcnt(0) drained before barrier -> data visible

    f16x8 bh[4], bl[4];
#pragma unroll
    for (int j = 0; j < 4; ++j) {
      bh[j] = *(const f16x8*)&Bs[0][wn + j * 16 + tx][swz];
      bl[j] = *(const f16x8*)&Bs[1][wn + j * 16 + tx][swz];
    }
#pragma unroll
    for (int i = 0; i < 4; ++i) {
      f16x8 ah = *(const f16x8*)&As[0][wm + i * 16 + tx][swz];
      f16x8 al = *(const f16x8*)&As[1][wm + i * 16 + tx][swz];
#pragma unroll
      for (int j = 0; j < 4; ++j) {
        acc[i][j] = __builtin_amdgcn_mfma_f32_16x16x32_f16(ah, bh[j], acc[i][j], 0, 0, 0);
        acc[i][j] = __builtin_amdgcn_mfma_f32_16x16x32_f16(ah, bl[j], acc[i][j], 0, 0, 0);
        acc[i][j] = __builtin_amdgcn_mfma_f32_16x16x32_f16(al, bh[j], acc[i][j], 0, 0, 0);
      }
    }
  }

  // ---- epilogue: score + argmin (first-index tie-break), round-2 verified logic ----
  __syncthreads();
  float* sF  = (float*)&As[0][0][0];
  float* zNl = sF;                 // [128]
  float* eNl = sF + 128;           // [128]
  float* sV  = sF + 256;           // [2][128]
  int*   sI  = (int*)(sF + 512);   // [2][128]
  if (t < 128) zNl[t] = zNorm[m0 + t];
  else         eNl[t - 128] = eNorm[n0 + t - 128];
  __syncthreads();

#pragma unroll
  for (int i = 0; i < 4; ++i) {
#pragma unroll
    for (int r = 0; r < 4; ++r) {
      const int rloc = wm + i * 16 + quad * 4 + r;
      const float zn = zNl[rloc];
      float bv = 3.4e38f;
      int bc = 0x7fffffff;
#pragma unroll
      for (int j = 0; j < 4; ++j) {
        const int col = wn + j * 16 + tx;
        float s = (zn + eNl[col]) - acc[i][j][r] * UNSCALE;
        if (s < bv) { bv = s; bc = n0 + col; }   // j ascending: strict < keeps lowest col
      }
#pragma unroll
      for (int off = 1; off < 16; off <<= 1) {
        float ov = __shfl_xor(bv, off, 64);
        int oc = __shfl_xor(bc, off, 64);
        if (ov < bv || (ov == bv && oc < bc)) { bv = ov; bc = oc; }
      }
      if (tx == 0) { sV[(w & 1) * 128 + rloc] = bv; sI[(w & 1) * 128 + rloc] = bc; }
    }
  }
  __syncthreads();
  if (t < 128) {
    float v0 = sV[t], v1 = sV[128 + t];
    int i0 = sI[t], i1 = sI[128 + t];
    int take1 = (v1 < v0);                 // tie -> half 0 (lower cols)
    pVal[(size_t)nt * N_ROWS + m0 + t] = take1 ? v1 : v0;
    pIdx[(size_t)nt * N_ROWS + m0 + t] = take1 ? i1 : i0;
  }
}

// ---------- fused: final argmin across NPART + gather z_q + loss ----------
__global__ __launch_bounds__(256) void k_post(const float* __restrict__ pVal,
                                              const int* __restrict__ pIdx,
                                              const float* __restrict__ z,
                                              const float* __restrict__ E,
                                              float* __restrict__ out,
                                              float* __restrict__ out_loss,
                                              float* __restrict__ out_idx) {
  int n = blockIdx.x * 256 + threadIdx.x;
  float mv = 3.4e38f;
  int mi = 0x7fffffff;
  for (int s2 = 0; s2 < NPART; ++s2) {
    float v = pVal[(size_t)s2 * N_ROWS + n];
    int id = pIdx[(size_t)s2 * N_ROWS + n];
    if (v < mv || (v == mv && id < mi)) { mv = v; mi = id; }
  }
  out_idx[n] = (float)mi;

  int b = n >> 10, hw = n & 1023;
  const float4* erow4 = (const float4*)(E + (size_t)mi * E_DIM);
  const float* zrow = z + (size_t)b * E_DIM * HW + hw;
  float* orow = out + (size_t)b * E_DIM * HW + hw;
  float s = 0.f;
  for (int c4 = 0; c4 < 64; ++c4) {
    float4 e4 = erow4[c4];
    float ev[4] = {e4.x, e4.y, e4.z, e4.w};
#pragma unroll
    for (int j2 = 0; j2 < 4; ++j2) {
      int c = c4 * 4 + j2;
      float zv = zrow[(size_t)c * HW];
      orow[(size_t)c * HW] = ev[j2];
      float d = ev[j2] - zv;
      s = fmaf(d, d, s);
    }
  }
  for (int off = 32; off > 0; off >>= 1) s += __shfl_down(s, off, 64);
  __shared__ float wsum[4];
  if ((threadIdx.x & 63) == 0) wsum[threadIdx.x >> 6] = s;
  __syncthreads();
  if (threadIdx.x == 0) {
    float tot = (wsum[0] + wsum[1]) + (wsum[2] + wsum[3]);
    atomicAdd(out_loss, tot * (1.25f / 2097152.f));
  }
}

extern "C" void kernel_launch(void* const* d_in, const int* in_sizes, int n_in,
                              void* d_out, int out_size, void* d_ws, size_t ws_size,
                              hipStream_t stream) {
  const float* z = (const float*)d_in[0];
  const float* E = (const float*)d_in[1];
  float* out = (float*)d_out;
  float* out_loss = out + 2097152;  // after z_q (8*256*32*32)
  float* out_idx = out + 2097153;

  // workspace (~32 MB): Ah|Al f16[8][8192][32], Bh|Bl f16[8][16384][32],
  //                     eNorm, zNorm, pVal, pIdx
  _Float16* Ah = (_Float16*)d_ws;
  _Float16* Al = Ah + (size_t)N_ROWS * E_DIM;
  _Float16* Bh = Al + (size_t)N_ROWS * E_DIM;
  _Float16* Bl = Bh + (size_t)N_E * E_DIM;
  float* eNorm = (float*)(Bl + (size_t)N_E * E_DIM);
  float* zNorm = eNorm + N_E;
  float* pVal = zNorm + N_ROWS;
  int* pIdx = (int*)(pVal + (size_t)NPART * N_ROWS);

  k_e_prep<<<N_E / 256, 256, 0, stream>>>(E, Bh, Bl, eNorm, out_loss);
  k_z_prep<<<N_ROWS / 256, 256, 0, stream>>>(z, Ah, Al, zNorm);
  k_scores_mfma<<<dim3(N_ROWS / 128, N_E / 128), 256, 0, stream>>>(
      Ah, Al, Bh, Bl, eNorm, zNorm, pVal, pIdx);
  k_post<<<N_ROWS / 256, 256, 0, stream>>>(pVal, pIdx, z, E, out, out_loss, out_idx);
}